// Round 4
// baseline (205.112 us; speedup 1.0000x reference)
//
#include <hip/hip_runtime.h>

// Multiprototypes: per-row squared distances to the 3 centers of the row's
// label, min-distance mean (loss1) and entropy-masked min-distance mean (loss2).
//
// B=262144, C=1000, K=3, D=64 (f32). HBM-bound: ~66 MB read -> ~10.4 us floor.
//
// R4: (1) intra-16-lane reduction via DPP row_ror rotate-add (pure VALU) --
// the previous 12 __shfl_xor/iter/wave put ~7.4 us of serialized issue on the
// per-CU DS pipe, same order as the HBM floor. (2) finalize fused into the
// main kernel via last-block-done (agent-scope atomics; per-XCD L2 is not
// coherent, so the reducer uses agent-scope atomic loads).

#define TH   0.95f
#define EPSF 1e-12f
#define NBLK 2048
#define BLK  256
#define ITERS 8   // rows_per_block(128) / rows_per_iter(16)

typedef float f4 __attribute__((ext_vector_type(4)));  // native vec for nt-load

// v += v rotated by N within each 16-lane DPP row (row_ror:N = ctrl 0x120|N).
template <int CTRL>
__device__ __forceinline__ float dpp_ror_add(float v) {
    int t = __builtin_amdgcn_mov_dpp(__float_as_int(v), CTRL, 0xf, 0xf, true);
    return v + __int_as_float(t);
}
__device__ __forceinline__ float row16_sum(float v) {
    v = dpp_ror_add<0x128>(v);  // ror 8
    v = dpp_ror_add<0x124>(v);  // ror 4
    v = dpp_ror_add<0x122>(v);  // ror 2
    v = dpp_ror_add<0x121>(v);  // ror 1
    return v;                   // all 16 lanes now hold the row sum
}

__global__ __launch_bounds__(BLK) void mp_main(
    const float* __restrict__ x,        // [B, 64]
    const int*   __restrict__ labels,   // [B]
    const float* __restrict__ centers,  // [1000, 3, 64]
    float*       __restrict__ partials, // [3*NBLK] + counter at [3*NBLK]
    float*       __restrict__ out,      // [2]
    float invB)
{
    const int tid  = threadIdx.x;
    const int lane = tid & 63;
    const int wave = tid >> 6;       // 0..3
    const int sub  = lane & 15;      // float4 slot within the row
    const int rsub = lane >> 4;      // row-within-wave 0..3

    const f4* __restrict__ x4 = (const f4*)x;
    const f4* __restrict__ c4 = (const f4*)centers;

    const int rowbase = blockIdx.x * (16 * ITERS) + wave * 4 + rsub;

    // Preload all labels (independent loads; breaks the per-iter chain).
    int labs[ITERS];
    #pragma unroll
    for (int t = 0; t < ITERS; ++t)
        labs[t] = __builtin_nontemporal_load(&labels[rowbase + t * 16]);

    float s1 = 0.f, s2 = 0.f, sc = 0.f;

    #pragma unroll
    for (int t = 0; t < ITERS; ++t) {
        const int row = rowbase + t * 16;

        // coalesced: the wave reads 4 contiguous rows = 1024 B (streaming)
        const f4 xv = __builtin_nontemporal_load(&x4[row * 16 + sub]);

        const f4* cb = c4 + labs[t] * 48 + sub;  // lab*(K=3)*(16 float4/row)
        const f4 cv0 = cb[0];
        const f4 cv1 = cb[16];
        const f4 cv2 = cb[32];

        f4 d;
        d = xv - cv0;
        float a0 = d.x * d.x + d.y * d.y + d.z * d.z + d.w * d.w;
        d = xv - cv1;
        float a1 = d.x * d.x + d.y * d.y + d.z * d.z + d.w * d.w;
        d = xv - cv2;
        float a2 = d.x * d.x + d.y * d.y + d.z * d.z + d.w * d.w;

        // intra-row (16-lane) sums via DPP -- no DS-pipe traffic
        a0 = row16_sum(a0);
        a1 = row16_sum(a1);
        a2 = row16_sum(a2);

        const float mn  = fminf(a0, fminf(a1, a2));
        const float mx  = fmaxf(a0, fmaxf(a1, a2));
        const float mid = a0 + a1 + a2 - mn - mx;   // second smallest

        const float d0 = mn + EPSF, d1 = mid + EPSF;
        const float p  = d0 / (d0 + d1);            // 0 < p <= 0.5
        const float q  = 1.f - p;
        const float ent = -(p * __log2f(p) + q * __log2f(q));
        const float msk = (ent <= TH) ? 1.f : 0.f;

        const float w = (sub == 0) ? 1.f : 0.f;     // count each row once
        s1 += w * mn;
        s2 += w * msk * mn;
        sc += w * msk;
    }

    // full-wave (64) butterfly reduce (once per block -- cheap)
    #pragma unroll
    for (int m = 1; m <= 32; m <<= 1) {
        s1 += __shfl_xor(s1, m);
        s2 += __shfl_xor(s2, m);
        sc += __shfl_xor(sc, m);
    }

    __shared__ float red[3][4];
    __shared__ int lastFlag;
    if (lane == 0) { red[0][wave] = s1; red[1][wave] = s2; red[2][wave] = sc; }
    __syncthreads();

    unsigned int* counter = (unsigned int*)&partials[3 * NBLK];
    if (tid == 0) {
        float p1 = red[0][0] + red[0][1] + red[0][2] + red[0][3];
        float p2 = red[1][0] + red[1][1] + red[1][2] + red[1][3];
        float p3 = red[2][0] + red[2][1] + red[2][2] + red[2][3];
        __hip_atomic_store(&partials[blockIdx.x],            p1, __ATOMIC_RELAXED, __HIP_MEMORY_SCOPE_AGENT);
        __hip_atomic_store(&partials[NBLK + blockIdx.x],     p2, __ATOMIC_RELAXED, __HIP_MEMORY_SCOPE_AGENT);
        __hip_atomic_store(&partials[2 * NBLK + blockIdx.x], p3, __ATOMIC_RELAXED, __HIP_MEMORY_SCOPE_AGENT);
        unsigned old = __hip_atomic_fetch_add(counter, 1u, __ATOMIC_ACQ_REL, __HIP_MEMORY_SCOPE_AGENT);
        lastFlag = (old == NBLK - 1);
    }
    __syncthreads();

    if (lastFlag) {
        // last-arriving block reduces all partials (agent-scope loads: bypass
        // potentially-stale per-XCD L2 lines from the 0xAA poison)
        float t1 = 0.f, t2 = 0.f, t3 = 0.f;
        for (int i = tid; i < NBLK; i += BLK) {
            t1 += __hip_atomic_load(&partials[i],            __ATOMIC_RELAXED, __HIP_MEMORY_SCOPE_AGENT);
            t2 += __hip_atomic_load(&partials[NBLK + i],     __ATOMIC_RELAXED, __HIP_MEMORY_SCOPE_AGENT);
            t3 += __hip_atomic_load(&partials[2 * NBLK + i], __ATOMIC_RELAXED, __HIP_MEMORY_SCOPE_AGENT);
        }
        #pragma unroll
        for (int m = 1; m <= 32; m <<= 1) {
            t1 += __shfl_xor(t1, m);
            t2 += __shfl_xor(t2, m);
            t3 += __shfl_xor(t3, m);
        }
        __syncthreads();   // red[] reuse
        if (lane == 0) { red[0][wave] = t1; red[1][wave] = t2; red[2][wave] = t3; }
        __syncthreads();
        if (tid == 0) {
            float f1 = red[0][0] + red[0][1] + red[0][2] + red[0][3];
            float f2 = red[1][0] + red[1][1] + red[1][2] + red[1][3];
            float f3 = red[2][0] + red[2][1] + red[2][2] + red[2][3];
            out[0] = f1 * invB;   // loss1 = mean(min_pos)
            out[1] = f2 / f3;     // loss2 = masked mean
        }
    }
}

extern "C" void kernel_launch(void* const* d_in, const int* in_sizes, int n_in,
                              void* d_out, int out_size, void* d_ws, size_t ws_size,
                              hipStream_t stream) {
    const float* x       = (const float*)d_in[0];
    const int*   labels  = (const int*)d_in[1];
    const float* centers = (const float*)d_in[2];
    float* out      = (float*)d_out;
    float* partials = (float*)d_ws;   // 3*NBLK floats + 1 counter
    const int B = in_sizes[1];        // 262144

    // zero the last-block counter (d_ws is re-poisoned 0xAA before every call)
    hipMemsetAsync((void*)(partials + 3 * NBLK), 0, sizeof(unsigned int), stream);
    mp_main<<<NBLK, BLK, 0, stream>>>(x, labels, centers, partials, out, 1.0f / (float)B);
}

// Round 5
// 113.309 us; speedup vs baseline: 1.8102x; 1.8102x over previous
//
#include <hip/hip_runtime.h>

// Multiprototypes: per-row squared distances to the 3 centers of the row's
// label, min-distance mean (loss1) and entropy-masked min-distance mean (loss2).
//
// B=262144, C=1000, K=3, D=64 (f32). HBM-bound: ~66 MB read -> ~10.4 us floor.
//
// R5: two-kernel structure (R4's fused last-block-done with agent-scope
// ACQ_REL atomics cost ~58 ns/block in L2 writeback/invalidate scans -- 120 us
// total, far worse than a second launch). Keeps R4's DPP row_ror intra-16
// reduction (pure VALU, no DS-pipe traffic) and nt streaming loads for x.

#define TH   0.95f
#define EPSF 1e-12f
#define NBLK 2048
#define BLK  256
#define ITERS 8   // rows_per_block(128) / rows_per_iter(16)

typedef float f4 __attribute__((ext_vector_type(4)));  // native vec for nt-load

// v += v rotated by N within each 16-lane DPP row (row_ror:N = ctrl 0x120|N).
template <int CTRL>
__device__ __forceinline__ float dpp_ror_add(float v) {
    int t = __builtin_amdgcn_mov_dpp(__float_as_int(v), CTRL, 0xf, 0xf, true);
    return v + __int_as_float(t);
}
__device__ __forceinline__ float row16_sum(float v) {
    v = dpp_ror_add<0x128>(v);  // ror 8
    v = dpp_ror_add<0x124>(v);  // ror 4
    v = dpp_ror_add<0x122>(v);  // ror 2
    v = dpp_ror_add<0x121>(v);  // ror 1
    return v;                   // all 16 lanes now hold the row sum
}

__global__ __launch_bounds__(BLK) void mp_main(
    const float* __restrict__ x,        // [B, 64]
    const int*   __restrict__ labels,   // [B]
    const float* __restrict__ centers,  // [1000, 3, 64]
    float*       __restrict__ partials) // [3 * NBLK]
{
    const int tid  = threadIdx.x;
    const int lane = tid & 63;
    const int wave = tid >> 6;       // 0..3
    const int sub  = lane & 15;      // float4 slot within the row
    const int rsub = lane >> 4;      // row-within-wave 0..3

    const f4* __restrict__ x4 = (const f4*)x;
    const f4* __restrict__ c4 = (const f4*)centers;

    const int rowbase = blockIdx.x * (16 * ITERS) + wave * 4 + rsub;

    // Preload all labels (independent loads; breaks the per-iter chain).
    int labs[ITERS];
    #pragma unroll
    for (int t = 0; t < ITERS; ++t)
        labs[t] = __builtin_nontemporal_load(&labels[rowbase + t * 16]);

    float s1 = 0.f, s2 = 0.f, sc = 0.f;

    #pragma unroll
    for (int t = 0; t < ITERS; ++t) {
        const int row = rowbase + t * 16;

        // coalesced: the wave reads 4 contiguous rows = 1024 B (streaming)
        const f4 xv = __builtin_nontemporal_load(&x4[row * 16 + sub]);

        const f4* cb = c4 + labs[t] * 48 + sub;  // lab*(K=3)*(16 float4/row)
        const f4 cv0 = cb[0];
        const f4 cv1 = cb[16];
        const f4 cv2 = cb[32];

        f4 d;
        d = xv - cv0;
        float a0 = d.x * d.x + d.y * d.y + d.z * d.z + d.w * d.w;
        d = xv - cv1;
        float a1 = d.x * d.x + d.y * d.y + d.z * d.z + d.w * d.w;
        d = xv - cv2;
        float a2 = d.x * d.x + d.y * d.y + d.z * d.z + d.w * d.w;

        // intra-row (16-lane) sums via DPP -- no DS-pipe traffic
        a0 = row16_sum(a0);
        a1 = row16_sum(a1);
        a2 = row16_sum(a2);

        const float mn  = fminf(a0, fminf(a1, a2));
        const float mx  = fmaxf(a0, fmaxf(a1, a2));
        const float mid = a0 + a1 + a2 - mn - mx;   // second smallest

        const float d0 = mn + EPSF, d1 = mid + EPSF;
        const float p  = d0 / (d0 + d1);            // 0 < p <= 0.5
        const float q  = 1.f - p;
        const float ent = -(p * __log2f(p) + q * __log2f(q));
        const float msk = (ent <= TH) ? 1.f : 0.f;

        const float w = (sub == 0) ? 1.f : 0.f;     // count each row once
        s1 += w * mn;
        s2 += w * msk * mn;
        sc += w * msk;
    }

    // full-wave (64) butterfly reduce (once per block -- cheap)
    #pragma unroll
    for (int m = 1; m <= 32; m <<= 1) {
        s1 += __shfl_xor(s1, m);
        s2 += __shfl_xor(s2, m);
        sc += __shfl_xor(sc, m);
    }

    __shared__ float red[3][4];
    if (lane == 0) { red[0][wave] = s1; red[1][wave] = s2; red[2][wave] = sc; }
    __syncthreads();
    if (tid == 0) {
        partials[blockIdx.x]            = red[0][0] + red[0][1] + red[0][2] + red[0][3];
        partials[NBLK + blockIdx.x]     = red[1][0] + red[1][1] + red[1][2] + red[1][3];
        partials[2 * NBLK + blockIdx.x] = red[2][0] + red[2][1] + red[2][2] + red[2][3];
    }
}

__global__ __launch_bounds__(BLK) void mp_final(
    const float* __restrict__ partials, float* __restrict__ out, float invB)
{
    const int tid  = threadIdx.x;
    const int lane = tid & 63;
    const int wave = tid >> 6;

    float s1 = 0.f, s2 = 0.f, sc = 0.f;
    for (int i = tid; i < NBLK; i += BLK) {
        s1 += partials[i];
        s2 += partials[NBLK + i];
        sc += partials[2 * NBLK + i];
    }
    #pragma unroll
    for (int m = 1; m <= 32; m <<= 1) {
        s1 += __shfl_xor(s1, m);
        s2 += __shfl_xor(s2, m);
        sc += __shfl_xor(sc, m);
    }
    __shared__ float red[3][4];
    if (lane == 0) { red[0][wave] = s1; red[1][wave] = s2; red[2][wave] = sc; }
    __syncthreads();
    if (tid == 0) {
        float t1 = red[0][0] + red[0][1] + red[0][2] + red[0][3];
        float t2 = red[1][0] + red[1][1] + red[1][2] + red[1][3];
        float t3 = red[2][0] + red[2][1] + red[2][2] + red[2][3];
        out[0] = t1 * invB;    // loss1 = mean(min_pos)
        out[1] = t2 / t3;      // loss2 = masked mean
    }
}

extern "C" void kernel_launch(void* const* d_in, const int* in_sizes, int n_in,
                              void* d_out, int out_size, void* d_ws, size_t ws_size,
                              hipStream_t stream) {
    const float* x       = (const float*)d_in[0];
    const int*   labels  = (const int*)d_in[1];
    const float* centers = (const float*)d_in[2];
    float* out      = (float*)d_out;
    float* partials = (float*)d_ws;   // 3*NBLK floats = 24 KB
    const int B = in_sizes[1];        // 262144

    mp_main<<<NBLK, BLK, 0, stream>>>(x, labels, centers, partials);
    mp_final<<<1, BLK, 0, stream>>>(partials, out, 1.0f / (float)B);
}